// Round 1
// baseline (1347.671 us; speedup 1.0000x reference)
//
#include <hip/hip_runtime.h>
#include <math.h>

// Problem constants
#define B_ 8
#define T_ 64
#define N_ 197
#define D_ 768
#define HIDD_ 3072   // HID*D
#define KF_ 8
#define KT_ 49

// Output layout (floats, concatenated in reference return order)
#define Z_SZ    (B_*KF_*KT_*D_)       // 2408448
#define FI_OFF  (Z_SZ)                // 2408448
#define FI_SZ   (B_*KF_)              // 64
#define TI_OFF  (FI_OFF + FI_SZ)      // 2408512
#define TI_SZ   (B_*KF_*KT_)          // 3136
#define FM_OFF  (TI_OFF + TI_SZ)      // 2411648
#define FM_SZ   (B_*T_)               // 512
#define TM_OFF  (FM_OFF + FM_SZ)      // 2412160

// Workspace layout (bytes)
#define WS_SCORE   0                          // 512 doubles = 4096
#define WS_FN64    4096                       // 512*768 doubles = 3145728
#define WS_H32     (4096 + 3145728)           // 512*768 floats = 1572864
#define WS_VALID   (WS_H32 + 1572864)         // 512 ints = 2048
#define WS_FIDX    (WS_VALID + 2048)          // 64 ints (pad to 256)
#define WS_TOK     (WS_FIDX + 256)            // 3136 ints = 12544

// ---------------------------------------------------------------------------
// Kernel A: masked-mean frame_repr (fp64), LayerNorm -> h32 (GEMM input),
// L2-normalized fn64 (for cosine sim), valid flags.
// One block per (b,t) row. 256 threads, 3 dims each.
// ---------------------------------------------------------------------------
__global__ __launch_bounds__(256) void kA(const float* __restrict__ x,
                                          const float* __restrict__ mask,
                                          const float* __restrict__ gamma,
                                          const float* __restrict__ beta,
                                          double* __restrict__ fn64,
                                          float* __restrict__ h32,
                                          int* __restrict__ validw) {
  const int row = blockIdx.x;          // b*T + t
  const int tid = threadIdx.x;
  __shared__ float  ms[N_];
  __shared__ double red[256];
  __shared__ double sh_denom, sh_mu, sh_sd, sh_nrm;
  const float* xr = x + (size_t)row * (N_ * D_);

  if (tid < N_) ms[tid] = mask[(size_t)row * N_ + tid];
  __syncthreads();

  // denom = clip(sum(mask), 1e-6)
  red[tid] = (tid < N_) ? (double)ms[tid] : 0.0;
  __syncthreads();
  for (int s = 128; s > 0; s >>= 1) { if (tid < s) red[tid] += red[tid + s]; __syncthreads(); }
  if (tid == 0) { double d = red[0]; sh_denom = (d > 1e-6) ? d : 1e-6; }
  __syncthreads();
  const double dn = sh_denom;

  // masked mean over n (fp64 accumulate)
  double a0 = 0.0, a1 = 0.0, a2 = 0.0;
  for (int n = 0; n < N_; n++) {
    const double mv = (double)ms[n];
    const float* xn = xr + n * D_;
    a0 += (double)xn[tid]       * mv;
    a1 += (double)xn[tid + 256] * mv;
    a2 += (double)xn[tid + 512] * mv;
  }
  const double f0 = a0 / dn, f1 = a1 / dn, f2 = a2 / dn;

  // mean
  red[tid] = f0 + f1 + f2; __syncthreads();
  for (int s = 128; s > 0; s >>= 1) { if (tid < s) red[tid] += red[tid + s]; __syncthreads(); }
  if (tid == 0) sh_mu = red[0] / (double)D_;
  __syncthreads();
  const double mu = sh_mu;

  // L2 norm of frame_repr (for cosine normalize, eps 1e-12)
  red[tid] = f0 * f0 + f1 * f1 + f2 * f2; __syncthreads();
  for (int s = 128; s > 0; s >>= 1) { if (tid < s) red[tid] += red[tid + s]; __syncthreads(); }
  if (tid == 0) { double nr = sqrt(red[0]); sh_nrm = (nr > 1e-12) ? nr : 1e-12; }
  __syncthreads();

  // variance (direct (x-mu)^2 mean, faithful to reference)
  red[tid] = (f0 - mu) * (f0 - mu) + (f1 - mu) * (f1 - mu) + (f2 - mu) * (f2 - mu);
  __syncthreads();
  for (int s = 128; s > 0; s >>= 1) { if (tid < s) red[tid] += red[tid + s]; __syncthreads(); }
  if (tid == 0) sh_sd = sqrt(red[0] / (double)D_ + 1e-5);
  __syncthreads();
  const double sd = sh_sd, nrm = sh_nrm;

  const size_t base = (size_t)row * D_;
  int d = tid;
  h32[base + d]  = (float)((f0 - mu) / sd * (double)gamma[d] + (double)beta[d]);
  fn64[base + d] = f0 / nrm;
  d = tid + 256;
  h32[base + d]  = (float)((f1 - mu) / sd * (double)gamma[d] + (double)beta[d]);
  fn64[base + d] = f1 / nrm;
  d = tid + 512;
  h32[base + d]  = (float)((f2 - mu) / sd * (double)gamma[d] + (double)beta[d]);
  fn64[base + d] = f2 / nrm;
  if (tid == 0) validw[row] = 1;  // clip(denom,1e-6) > 0 is always true
}

// ---------------------------------------------------------------------------
// Kernel B: score = gelu(h @ W1 + b1) @ W2, fused (no h1 materialization).
// Tiled fp32 GEMM, M=512 N=3072 K=768; Mtile=32, Ntile=128, BK=64,
// 256 threads with 4x4 micro-tiles; fp64 GELU/W2 epilogue + fp64 atomicAdd.
// Grid: (3072/128=24, 512/32=16).
// ---------------------------------------------------------------------------
__global__ __launch_bounds__(256) void kB(const float* __restrict__ h32,
                                          const float* __restrict__ W1,
                                          const float* __restrict__ b1,
                                          const float* __restrict__ W2,
                                          double* __restrict__ score) {
  const int n0 = blockIdx.x * 128;
  const int m0 = blockIdx.y * 32;
  const int tid = threadIdx.x;
  const int tx = tid & 31;   // 32 col-groups of 4
  const int ty = tid >> 5;   // 8 row-groups of 4
  __shared__ float As[64 * 33];   // [k][m], padded
  __shared__ float Bs[64 * 128];  // [k][n]
  float acc[4][4];
#pragma unroll
  for (int r = 0; r < 4; r++)
#pragma unroll
    for (int c = 0; c < 4; c++) acc[r][c] = 0.0f;

  for (int kc = 0; kc < 12; kc++) {
    const int k0 = kc * 64;
#pragma unroll
    for (int it = 0; it < 8; it++) {           // A: 32x64 = 2048 floats
      int idx = tid + (it << 8);
      int k = idx & 63, m = idx >> 6;
      As[k * 33 + m] = h32[(size_t)(m0 + m) * D_ + k0 + k];
    }
#pragma unroll
    for (int it = 0; it < 8; it++) {           // B: 64x128 = 2048 float4
      int idx = tid + (it << 8);
      int k = idx >> 5, n4 = idx & 31;
      const float4 v = *(const float4*)(W1 + (size_t)(k0 + k) * HIDD_ + n0 + (n4 << 2));
      *(float4*)(Bs + k * 128 + (n4 << 2)) = v;
    }
    __syncthreads();
#pragma unroll 16
    for (int kk = 0; kk < 64; kk++) {
      float a[4], bb[4];
#pragma unroll
      for (int r = 0; r < 4; r++) a[r] = As[kk * 33 + ty * 4 + r];
#pragma unroll
      for (int c = 0; c < 4; c++) bb[c] = Bs[kk * 128 + tx * 4 + c];
#pragma unroll
      for (int r = 0; r < 4; r++)
#pragma unroll
        for (int c = 0; c < 4; c++) acc[r][c] += a[r] * bb[c];
    }
    __syncthreads();
  }

  // Epilogue: exact GELU (fp64) * W2, reduce over this block's 128 cols per row
  double part[4] = {0.0, 0.0, 0.0, 0.0};
#pragma unroll
  for (int r = 0; r < 4; r++) {
#pragma unroll
    for (int c = 0; c < 4; c++) {
      const int gn = n0 + tx * 4 + c;
      const double v = (double)(acc[r][c] + b1[gn]);
      const double g = 0.5 * v * (1.0 + erf(v * 0.7071067811865475244));
      part[r] += g * (double)W2[gn];
    }
  }
#pragma unroll
  for (int r = 0; r < 4; r++) {
    double s = part[r];
#pragma unroll
    for (int off = 16; off > 0; off >>= 1) s += __shfl_down(s, off, 32);
    if (tx == 0) atomicAdd(&score[m0 + ty * 4 + r], s);
  }
}

// ---------------------------------------------------------------------------
// Kernel D: facility-location greedy frame selection. One block per batch.
// sim (fp64) staged via LDS chunks; greedy runs on wave 0 (64 lanes = T).
// Also writes frame_idx + frame_mask outputs directly.
// ---------------------------------------------------------------------------
__global__ __launch_bounds__(1024) void kD(const double* __restrict__ fn64,
                                           const double* __restrict__ score,
                                           const int* __restrict__ validw,
                                           const float* __restrict__ b2,
                                           int* __restrict__ fidxw,
                                           float* __restrict__ out_fidx,
                                           float* __restrict__ out_fmask) {
  const int b = blockIdx.x;
  const int tid = threadIdx.x;
  __shared__ double fnS[64 * 65];   // chunk [t][kk], padded
  __shared__ double sim[64 * 64];
  __shared__ double scoreS[64];
  __shared__ double bc[64];
  __shared__ int chosenS[64];
  __shared__ int validS[64];

  const int i = tid >> 4;            // 0..63 row
  const int jb = (tid & 15) << 2;    // 0..60 col group of 4
  double acc[4] = {0.0, 0.0, 0.0, 0.0};

  for (int c = 0; c < 12; c++) {
#pragma unroll
    for (int it = 0; it < 4; it++) {
      int idx = tid + (it << 10);
      int t = idx >> 6, kk = idx & 63;
      fnS[t * 65 + kk] = fn64[((size_t)(b * T_ + t)) * D_ + c * 64 + kk];
    }
    __syncthreads();
#pragma unroll 8
    for (int kk = 0; kk < 64; kk++) {
      const double fv = fnS[i * 65 + kk];
      acc[0] += fv * fnS[(jb + 0) * 65 + kk];
      acc[1] += fv * fnS[(jb + 1) * 65 + kk];
      acc[2] += fv * fnS[(jb + 2) * 65 + kk];
      acc[3] += fv * fnS[(jb + 3) * 65 + kk];
    }
    __syncthreads();
  }
#pragma unroll
  for (int q = 0; q < 4; q++) sim[i * 64 + jb + q] = acc[q];
  if (tid < 64) {
    scoreS[tid]  = score[b * T_ + tid] + (double)b2[0];
    validS[tid]  = validw[b * T_ + tid];
    bc[tid]      = 0.0;
    chosenS[tid] = 0;
  }
  __syncthreads();

  for (int step = 0; step < KF_; step++) {
    if (tid < 64) {
      // cov_gain(j=tid) = sum_i max(bc[i], sim[i][j]) - sum_i bc[i]
      double g = 0.0;
      for (int ii = 0; ii < 64; ii++) g += fmax(bc[ii], sim[ii * 64 + tid]);
      double bs = bc[tid];
#pragma unroll
      for (int off = 32; off > 0; off >>= 1) bs += __shfl_down(bs, off, 64);
      bs = __shfl(bs, 0, 64);
      double tot = g - bs + 0.5 * scoreS[tid];
      if (!validS[tid] || chosenS[tid]) tot = -INFINITY;
      // argmax, first-occurrence tie-break
      double bv = tot; int bi = tid;
#pragma unroll
      for (int off = 32; off > 0; off >>= 1) {
        double ov = __shfl_down(bv, off, 64);
        int    oi = __shfl_down(bi, off, 64);
        if (ov > bv || (ov == bv && oi < bi)) { bv = ov; bi = oi; }
      }
      bi = __shfl(bi, 0, 64);
      bc[tid] = fmax(bc[tid], sim[tid * 64 + bi]);
      if (tid == bi) chosenS[tid] = 1;
      if (tid == 0) {
        fidxw[b * KF_ + step] = bi;
        out_fidx[b * KF_ + step] = (float)bi;
      }
    }
    __syncthreads();
  }
  if (tid < 64) out_fmask[b * T_ + tid] = chosenS[tid] ? 1.0f : 0.0f;
}

// ---------------------------------------------------------------------------
// Kernel E: greedy k-center (farthest point sampling), one block per
// (b, selected frame). 1024 threads = 16 waves; each wave handles rows
// n = wave, wave+16, ...; lane covers 12 dims. All distances fp64.
// ---------------------------------------------------------------------------
__global__ __launch_bounds__(1024) void kE(const float* __restrict__ x,
                                           const float* __restrict__ mask,
                                           const int* __restrict__ fidxw,
                                           int* __restrict__ tokw) {
  const int pair = blockIdx.x;        // b*KF + kf
  const int b = pair >> 3;
  const int tid = threadIdx.x;
  const int wave = tid >> 6;
  const int lane = tid & 63;
  const int fi = fidxw[pair];
  const float* X    = x + ((size_t)(b * T_ + fi)) * (N_ * D_);
  const float* mrow = mask + (size_t)(b * T_ + fi) * N_;

  __shared__ double md[N_];
  __shared__ double C[D_];
  __shared__ int validS[N_];
  __shared__ int candS;

  if (tid < N_) validS[tid] = (mrow[tid] > 0.5f) ? 1 : 0;
  __syncthreads();

  // d0 = valid ? ||X_n||^2 : -inf
  for (int n = wave; n < N_; n += 16) {
    const float* row = X + (size_t)n * D_ + lane * 12;
    double s = 0.0;
#pragma unroll
    for (int j = 0; j < 12; j++) { double v = (double)row[j]; s += v * v; }
#pragma unroll
    for (int off = 32; off > 0; off >>= 1) s += __shfl_down(s, off, 64);
    if (lane == 0) md[n] = validS[n] ? s : -INFINITY;
  }
  __syncthreads();

  // argmax helper inlined each round (wave 0)
  if (tid < 64) {
    double bv = md[tid]; int bi = tid;
    for (int n = tid + 64; n < N_; n += 64) {
      double v = md[n];
      if (v > bv) { bv = v; bi = n; }
    }
#pragma unroll
    for (int off = 32; off > 0; off >>= 1) {
      double ov = __shfl_down(bv, off, 64);
      int    oi = __shfl_down(bi, off, 64);
      if (ov > bv || (ov == bv && oi < bi)) { bv = ov; bi = oi; }
    }
    if (tid == 0) candS = bi;
  }
  __syncthreads();
  int cand = candS;
  if (tid == 0) tokw[pair * KT_] = cand;

  for (int k = 1; k < KT_; k++) {
    // stage candidate row in fp64
    if (tid < D_) C[tid] = (double)X[(size_t)cand * D_ + tid];
    __syncthreads();
    for (int n = wave; n < N_; n += 16) {
      const float* row = X + (size_t)n * D_ + lane * 12;
      const double* cc = C + lane * 12;
      double s = 0.0;
#pragma unroll
      for (int j = 0; j < 12; j++) { double v = (double)row[j] - cc[j]; s += v * v; }
#pragma unroll
      for (int off = 32; off > 0; off >>= 1) s += __shfl_down(s, off, 64);
      if (lane == 0) {
        if (!validS[n]) md[n] = -1.0;
        else {
          double dist = sqrt(s);
          md[n] = (k == 1) ? dist : fmin(md[n], dist);
        }
      }
    }
    __syncthreads();
    if (tid < 64) {
      double bv = md[tid]; int bi = tid;
      for (int n = tid + 64; n < N_; n += 64) {
        double v = md[n];
        if (v > bv) { bv = v; bi = n; }
      }
#pragma unroll
      for (int off = 32; off > 0; off >>= 1) {
        double ov = __shfl_down(bv, off, 64);
        int    oi = __shfl_down(bi, off, 64);
        if (ov > bv || (ov == bv && oi < bi)) { bv = ov; bi = oi; }
      }
      if (tid == 0) candS = bi;
    }
    __syncthreads();
    cand = candS;
    if (tid == 0) tokw[pair * KT_ + k] = cand;
  }
}

// ---------------------------------------------------------------------------
// Kernel F: gather z rows, write token_idx (as float), scatter token_mask.
// One block per (b,kf,kt) = 3136 blocks.
// ---------------------------------------------------------------------------
__global__ __launch_bounds__(256) void kF(const float* __restrict__ x,
                                          const int* __restrict__ fidxw,
                                          const int* __restrict__ tokw,
                                          float* __restrict__ out) {
  const int row = blockIdx.x;          // pair*KT + kt
  const int pair = row / KT_;
  const int b = pair >> 3;
  const int tid = threadIdx.x;
  const int fi = fidxw[pair];
  const int tok = tokw[row];
  const float* src = x + (((size_t)(b * T_ + fi)) * N_ + tok) * D_;
  float* dst = out + (size_t)row * D_;
  dst[tid]       = src[tid];
  dst[tid + 256] = src[tid + 256];
  dst[tid + 512] = src[tid + 512];
  if (tid == 0) {
    out[TI_OFF + row] = (float)tok;
    out[TM_OFF + (size_t)(b * T_ + fi) * N_ + tok] = 1.0f;
  }
}

// ---------------------------------------------------------------------------
extern "C" void kernel_launch(void* const* d_in, const int* in_sizes, int n_in,
                              void* d_out, int out_size, void* d_ws, size_t ws_size,
                              hipStream_t stream) {
  (void)in_sizes; (void)n_in; (void)ws_size;
  const float* x     = (const float*)d_in[0];
  const float* mask  = (const float*)d_in[1];
  const float* gamma = (const float*)d_in[2];
  const float* beta  = (const float*)d_in[3];
  const float* W1    = (const float*)d_in[4];
  const float* b1    = (const float*)d_in[5];
  const float* W2    = (const float*)d_in[6];
  const float* b2    = (const float*)d_in[7];
  float* out = (float*)d_out;
  char* ws = (char*)d_ws;

  double* score = (double*)(ws + WS_SCORE);
  double* fn64  = (double*)(ws + WS_FN64);
  float*  h32   = (float*)(ws + WS_H32);
  int*    validw = (int*)(ws + WS_VALID);
  int*    fidxw  = (int*)(ws + WS_FIDX);
  int*    tokw   = (int*)(ws + WS_TOK);

  // zero outputs (token_mask needs zeros; rest overwritten) and score accum
  hipMemsetAsync(d_out, 0, (size_t)out_size * sizeof(float), stream);
  hipMemsetAsync(score, 0, (size_t)B_ * T_ * sizeof(double), stream);

  kA<<<B_ * T_, 256, 0, stream>>>(x, mask, gamma, beta, fn64, h32, validw);
  kB<<<dim3(HIDD_ / 128, (B_ * T_) / 32), 256, 0, stream>>>(h32, W1, b1, W2, score);
  kD<<<B_, 1024, 0, stream>>>(fn64, score, validw, b2, fidxw, out + FI_OFF, out + FM_OFF);
  kE<<<B_ * KF_, 1024, 0, stream>>>(x, mask, fidxw, tokw);
  kF<<<B_ * KF_ * KT_, 256, 0, stream>>>(x, fidxw, tokw, out);
}